// Round 13
// baseline (713.293 us; speedup 1.0000x reference)
//
#include <hip/hip_runtime.h>
#include <hip/hip_cooperative_groups.h>

// ---------------------------------------------------------------------------
// RelGraphConv x3 + action mask, MI355X (gfx950) — round 13
// R8..R12 plateau at ~220us with kernel-time sum ~150us -> ~60-80us of
// inter-dispatch gaps is the top cost. This round: ONE cooperative launch,
// grid.sync() between phases (also provides intra-launch producer/consumer
// ordering, fixing the R7-class hazard properly). Grid-stride persistent
// loops; __launch_bounds__(256,4) -> 4 blocks/CU co-resident. Fallback to
// the R12 8-dispatch path if cooperative launch is unavailable.
// ---------------------------------------------------------------------------

#define STRIDE 64    // bucket capacity; P(deg>=64) astronomically small
#define BINCAP 2560  // records per bin; mean 2048, sigma~45 -> 11 sigma margin

typedef unsigned short ushortT;
typedef __attribute__((ext_vector_type(8))) short short8;   // 8 bf16 (4 VGPRs)
typedef __attribute__((ext_vector_type(4))) float f32x4;    // MFMA C/D

struct GP {
    const float* x; const int* src; const int* dst; const int* et;
    const int* cellsz; const int* maxsz;
    const float* W1; const float* loop1; const float* b1;
    const float* W2; const float* loop2; const float* b2;
    const float* W3; const float* loop3; const float* b3;
    float* out;
    ushortT* hrelb; ushortT* H1b; ushortT* Sb;
    float* hrel3; float* H3; int* cnt; int* eidx;
    ushortT* BP1; ushortT* BP2; float* minval;
    int* bincnt; int2* binbuf;
    int N, E, NBINS, NBA, NTILES, NB_W, NB_N;
};

__device__ inline ushortT f2bf(float f) {
    union { float f; unsigned u; } v; v.f = f;
    unsigned r = v.u + 0x7FFFu + ((v.u >> 16) & 1u);   // RNE
    return (ushortT)(r >> 16);
}
__device__ inline float bf2f(ushortT h) {
    union { unsigned u; float f; } v; v.u = ((unsigned)h) << 16;
    return v.f;
}
__device__ inline void atomicMinF(float* addr, float v) {
    if (v >= 0.f) atomicMin((int*)addr, __float_as_int(v));
    else          atomicMax((unsigned int*)addr, __float_as_uint(v));
}

// ---- phase bodies (shared by mega kernel and fallback kernels) -------------

// work item g in [0,4608): pack BP1/BP2, init minval. (bincnt zeroed by memset)
__device__ __forceinline__ void dev_pack_init(int g, const GP& p) {
    if (g == 0) *(int*)p.minval = 0x7f7f7f7f;  // 3.39e38
    if (g < 3072) {
        int l = g & 63, ks = (g >> 6) & 3, ct = g >> 8;
        int c = ct * 16 + (l & 15);
        int mat = c >> 6, cc = c & 63;
        int kbase = ks * 32 + (l >> 4) * 8;
        ushortT* dstp = p.BP1 + (size_t)g * 8;
#pragma unroll
        for (int j = 0; j < 8; ++j) {
            int k = kbase + j;
            float v = (mat < 2) ? p.W1[((size_t)mat * 128 + k) * 64 + cc]
                                : p.loop1[(size_t)k * 64 + cc];
            dstp[j] = f2bf(v);
        }
    } else if (g < 4608) {
        int s = g - 3072;                 // 0..1535: ct*384 + ks*64 + l
        int l = s & 63;
        int ks = (s >> 6) % 6;
        int ct = s / 384;
        int c = ct * 16 + (l & 15);
        int kbase = ks * 32 + (l >> 4) * 8;
        ushortT* dstp = p.BP2 + (size_t)s * 8;
#pragma unroll
        for (int j = 0; j < 8; ++j) {
            int k = kbase + j;            // 0..191: [W2_0 | W2_1 | loop2]
            float v = (k < 128) ? p.W2[(size_t)k * 64 + c]
                                : p.loop2[(size_t)(k - 128) * 64 + c];
            dstp[j] = f2bf(v);
        }
    }
}

__device__ __forceinline__ void dev_phaseA_chunk(
    int chunk, int t, int* hist, int* gbase, ushortT* rnk, const GP& p) {
    for (int i = t; i < p.NBINS; i += 256) hist[i] = 0;
    __syncthreads();
    const int base = chunk * 4096;
#pragma unroll
    for (int i = 0; i < 16; ++i) {
        int e = base + t + i * 256;
        if (e < p.E) {
            int bb = p.dst[e] >> 7;
            rnk[t + i * 256] = (ushortT)atomicAdd(&hist[bb], 1);
        }
    }
    __syncthreads();
    for (int i = t; i < p.NBINS; i += 256) {
        int h = hist[i];
        gbase[i] = h ? atomicAdd(&p.bincnt[i], h) : 0;
    }
    __syncthreads();
#pragma unroll
    for (int i = 0; i < 16; ++i) {
        int e = base + t + i * 256;
        if (e < p.E) {
            int dd = p.dst[e];
            int bb = dd >> 7;
            int v = p.et[e] * p.N + p.src[e];
            int pos = gbase[bb] + (int)rnk[t + i * 256];
            if (pos < BINCAP)
                p.binbuf[(size_t)bb * BINCAP + pos] = make_int2(dd, v);
        }
    }
}

__device__ __forceinline__ void dev_gemm1_tile(int tile, int t, const GP& p) {
    const int w = t >> 6, lane = t & 63;
    const int rowbase = (tile * 4 + w) * 16;
    const int m = lane & 15, quad = lane >> 4;
    const int nclamp = min(rowbase + m, p.N - 1);

    short8 a[4];
    const float* xp = p.x + (size_t)nclamp * 128 + quad * 8;
#pragma unroll
    for (int ks = 0; ks < 4; ++ks) {
        float4 g0 = *(const float4*)(xp + ks * 32);
        float4 g1 = *(const float4*)(xp + ks * 32 + 4);
        a[ks][0] = (short)f2bf(g0.x); a[ks][1] = (short)f2bf(g0.y);
        a[ks][2] = (short)f2bf(g0.z); a[ks][3] = (short)f2bf(g0.w);
        a[ks][4] = (short)f2bf(g1.x); a[ks][5] = (short)f2bf(g1.y);
        a[ks][6] = (short)f2bf(g1.z); a[ks][7] = (short)f2bf(g1.w);
    }
    f32x4 acc[12];
#pragma unroll
    for (int ct = 0; ct < 12; ++ct) acc[ct] = (f32x4){0.f, 0.f, 0.f, 0.f};
#pragma unroll
    for (int ks = 0; ks < 4; ++ks) {
#pragma unroll
        for (int ct = 0; ct < 12; ++ct) {
            short8 b = *(const short8*)&p.BP1[((size_t)(ct * 4 + ks) * 64 + lane) * 8];
            acc[ct] = __builtin_amdgcn_mfma_f32_16x16x32_bf16(a[ks], b, acc[ct], 0, 0, 0);
        }
    }
    const int node0 = rowbase + quad * 4;
#pragma unroll
    for (int ct = 0; ct < 12; ++ct) {
        int c = ct * 16 + m;
        int mat = c >> 6, cc = c & 63;
        float bias = (mat == 2) ? p.b1[cc] : 0.f;
#pragma unroll
        for (int j = 0; j < 4; ++j) {
            int n = node0 + j;
            if (n < p.N) {
                float v = acc[ct][j] + bias;
                if (mat < 2) p.hrelb[((size_t)mat * p.N + n) * 64 + cc] = f2bf(v);
                else         p.H1b[(size_t)n * 64 + cc] = f2bf(v);
            }
        }
    }
}

__device__ __forceinline__ void dev_phaseB_bin(int b, int t, int* lcnt, const GP& p) {
    if (t < 128) lcnt[t] = 0;
    __syncthreads();
    const int cb = min(p.bincnt[b], BINCAP);
    const int2* buf = p.binbuf + (size_t)b * BINCAP;
    for (int i = t; i < cb; i += 256) {
        int2 rec = buf[i];
        int r = atomicAdd(&lcnt[rec.x & 127], 1);
        if (r < STRIDE) p.eidx[(size_t)rec.x * STRIDE + r] = rec.y;
    }
    __syncthreads();
    int node = b * 128 + t;
    if (t < 128 && node < p.N) p.cnt[node] = min(lcnt[t], STRIDE);
}

__device__ __forceinline__ float gather_accum(
    const ushortT* __restrict__ hb, int my, int deg, int lane, float acc) {
    for (int j = 0; j < deg; j += 16) {
        float v[16];
#pragma unroll
        for (int q = 0; q < 16; ++q) {
            int jj = j + q;
            int sel = (jj < deg) ? jj : 0;
            int id = __shfl(my, sel, 64);
            float wgt = (jj < deg) ? 1.f : 0.f;
            v[q] = wgt * bf2f(hb[(size_t)id * 64 + lane]);
        }
        float s0 = (v[0] + v[1]) + (v[2] + v[3]);
        float s1 = (v[4] + v[5]) + (v[6] + v[7]);
        float s2 = (v[8] + v[9]) + (v[10] + v[11]);
        float s3 = (v[12] + v[13]) + (v[14] + v[15]);
        acc += (s0 + s1) + (s2 + s3);
    }
    return acc;
}

__device__ __forceinline__ void dev_agg1_group(int blk, int t, const GP& p) {
    int node = blk * 4 + (t >> 6);
    if (node >= p.N) return;  // no syncs below: safe in helper
    int lane = t & 63;
    int deg = p.cnt[node];
    int my = (lane < deg) ? p.eidx[(size_t)node * STRIDE + lane] : 0;
    float acc = bf2f(p.H1b[(size_t)node * 64 + lane]);
    acc = gather_accum(p.hrelb, my, deg, lane, acc);
    p.H1b[(size_t)node * 64 + lane] = f2bf(fmaxf(acc, 0.f));
}

__device__ __forceinline__ void dev_agg2_group(int blk, int t, const GP& p) {
    int node = blk * 4 + (t >> 6);
    if (node >= p.N) return;
    int lane = t & 63;
    int deg = p.cnt[node];
    int my = (lane < deg) ? p.eidx[(size_t)node * STRIDE + lane] : 0;
    float a0 = 0.f, a1 = 0.f;
    for (int j = 0; j < deg; j += 16) {
        float v[16], w0[16], w1[16];
#pragma unroll
        for (int q = 0; q < 16; ++q) {
            int jj = j + q;
            int sel = (jj < deg) ? jj : 0;
            int id = __shfl(my, sel, 64);       // id = rel*N + src
            int rel = (id >= p.N) ? 1 : 0;
            int row = id - rel * p.N;
            float live = (jj < deg) ? 1.f : 0.f;
            w0[q] = rel ? 0.f : live;
            w1[q] = rel ? live : 0.f;
            v[q] = bf2f(p.H1b[(size_t)row * 64 + lane]);
        }
#pragma unroll
        for (int q = 0; q < 16; ++q) {
            a0 += w0[q] * v[q];
            a1 += w1[q] * v[q];
        }
    }
    p.Sb[(size_t)node * 64 + lane] = f2bf(a0);
    p.Sb[((size_t)p.N + node) * 64 + lane] = f2bf(a1);
}

__device__ __forceinline__ void dev_gemm23_tile(int tile, int t, const GP& p) {
    const int w = t >> 6, lane = t & 63;
    const int rowbase = (tile * 4 + w) * 16;
    const int m = lane & 15, quad = lane >> 4;
    const int nclamp = min(rowbase + m, p.N - 1);

    f32x4 acc[4];
#pragma unroll
    for (int ct = 0; ct < 4; ++ct) acc[ct] = (f32x4){0.f, 0.f, 0.f, 0.f};
#pragma unroll
    for (int ks = 0; ks < 6; ++ks) {
        const ushortT* base =
            (ks < 2) ? (p.Sb + (size_t)nclamp * 64)
          : (ks < 4) ? (p.Sb + ((size_t)p.N + nclamp) * 64)
                     : (p.H1b + (size_t)nclamp * 64);
        short8 a = *(const short8*)(base + (ks & 1) * 32 + quad * 8);
#pragma unroll
        for (int ct = 0; ct < 4; ++ct) {
            short8 b = *(const short8*)&p.BP2[((size_t)(ct * 6 + ks) * 64 + lane) * 8];
            acc[ct] = __builtin_amdgcn_mfma_f32_16x16x32_bf16(a, b, acc[ct], 0, 0, 0);
        }
    }
    float h2[4][4];
#pragma unroll
    for (int ct = 0; ct < 4; ++ct) {
        float bias = p.b2[ct * 16 + m];
#pragma unroll
        for (int j = 0; j < 4; ++j) h2[ct][j] = fmaxf(acc[ct][j] + bias, 0.f);
    }
    float w3v[4][6];
#pragma unroll
    for (int ct = 0; ct < 4; ++ct) {
        int k = ct * 16 + m;
        w3v[ct][0] = p.W3[k * 2 + 0];
        w3v[ct][1] = p.W3[k * 2 + 1];
        w3v[ct][2] = p.W3[(64 + k) * 2 + 0];
        w3v[ct][3] = p.W3[(64 + k) * 2 + 1];
        w3v[ct][4] = p.loop3[k * 2 + 0];
        w3v[ct][5] = p.loop3[k * 2 + 1];
    }
    float pr[4][6];
#pragma unroll
    for (int j = 0; j < 4; ++j)
#pragma unroll
        for (int c = 0; c < 6; ++c) pr[j][c] = 0.f;
#pragma unroll
    for (int j = 0; j < 4; ++j)
#pragma unroll
        for (int ct = 0; ct < 4; ++ct)
#pragma unroll
            for (int c = 0; c < 6; ++c) pr[j][c] += h2[ct][j] * w3v[ct][c];
#pragma unroll
    for (int mask = 1; mask <= 8; mask <<= 1) {
#pragma unroll
        for (int j = 0; j < 4; ++j)
#pragma unroll
            for (int c = 0; c < 6; ++c) pr[j][c] += __shfl_xor(pr[j][c], mask, 64);
    }
    if (m == 0) {
#pragma unroll
        for (int j = 0; j < 4; ++j) {
            int n = rowbase + quad * 4 + j;
            if (n < p.N) {
                p.hrel3[(size_t)n * 2 + 0] = pr[j][0];
                p.hrel3[(size_t)n * 2 + 1] = pr[j][1];
                p.hrel3[((size_t)p.N + n) * 2 + 0] = pr[j][2];
                p.hrel3[((size_t)p.N + n) * 2 + 1] = pr[j][3];
                p.H3[(size_t)n * 2 + 0] = pr[j][4] + p.b3[0];
                p.H3[(size_t)n * 2 + 1] = pr[j][5] + p.b3[1];
            }
        }
    }
}

__device__ __forceinline__ void dev_agg3min_group(int blk, int t, float* smin, const GP& p) {
    int n = blk * 256 + t;
    float v = 3.4e38f;
    if (n < p.N) {
        float a0 = p.H3[n * 2 + 0], a1 = p.H3[n * 2 + 1];
        int deg = p.cnt[n];
        const int* row = &p.eidx[(size_t)n * STRIDE];
        for (int j = 0; j < deg; j += 8) {
            float2 q[8];
            float wg[8];
#pragma unroll
            for (int qq = 0; qq < 8; ++qq) {
                int jj = j + qq;
                int sel = (jj < deg) ? jj : 0;
                int idx = row[sel];
                wg[qq] = (jj < deg) ? 1.f : 0.f;
                q[qq] = *(const float2*)&p.hrel3[(size_t)idx * 2];
            }
#pragma unroll
            for (int qq = 0; qq < 8; ++qq) {
                a0 += wg[qq] * q[qq].x;
                a1 += wg[qq] * q[qq].y;
            }
        }
        p.H3[n * 2 + 0] = a0;
        p.H3[n * 2 + 1] = a1;
        v = fminf(a0, a1);
    }
#pragma unroll
    for (int mm = 32; mm >= 1; mm >>= 1) v = fminf(v, __shfl_xor(v, mm, 64));
    if ((t & 63) == 0) smin[t >> 6] = v;
    __syncthreads();
    if (t == 0)
        atomicMinF(p.minval, fminf(fminf(smin[0], smin[1]), fminf(smin[2], smin[3])));
}

__device__ __forceinline__ void dev_mask_group(int blk, int t, const GP& p) {
    int n = blk * 256 + t;
    if (n >= p.N) return;
    float m = p.minval[0] - 1.0f;
    bool up = p.cellsz[n] >= p.maxsz[n] - 1;
    bool lo = p.cellsz[n] == 0;
    p.out[n * 2 + 0] = up ? m : p.H3[n * 2 + 0];
    p.out[n * 2 + 1] = lo ? m : p.H3[n * 2 + 1];
}

// ---- mega: all phases, one cooperative launch ------------------------------
__global__ __launch_bounds__(256, 4) void mega_kernel(GP p) {
    cooperative_groups::grid_group grid = cooperative_groups::this_grid();
    __shared__ int hist[512];
    __shared__ int gbase[512];
    __shared__ ushortT rnk[4096];
    __shared__ int lcnt[128];
    __shared__ float smin[4];
    const int t = (int)threadIdx.x;
    const int nb = (int)gridDim.x;

    for (int g = (int)blockIdx.x * 256 + t; g < 4608; g += nb * 256)
        dev_pack_init(g, p);
    grid.sync();

    for (int task = (int)blockIdx.x; task < p.NBA + p.NTILES; task += nb) {
        if (task < p.NBA) dev_phaseA_chunk(task, t, hist, gbase, rnk, p);
        else              dev_gemm1_tile(task - p.NBA, t, p);
        __syncthreads();  // LDS reuse fence between loop iterations
    }
    grid.sync();

    for (int b = (int)blockIdx.x; b < p.NBINS; b += nb) {
        dev_phaseB_bin(b, t, lcnt, p);
        __syncthreads();
    }
    grid.sync();

    for (int blk = (int)blockIdx.x; blk < p.NB_W; blk += nb)
        dev_agg1_group(blk, t, p);
    grid.sync();

    for (int blk = (int)blockIdx.x; blk < p.NB_W; blk += nb)
        dev_agg2_group(blk, t, p);
    grid.sync();

    for (int tile = (int)blockIdx.x; tile < p.NTILES; tile += nb)
        dev_gemm23_tile(tile, t, p);
    grid.sync();

    for (int blk = (int)blockIdx.x; blk < p.NB_N; blk += nb) {
        dev_agg3min_group(blk, t, smin, p);
        __syncthreads();
    }
    grid.sync();

    for (int blk = (int)blockIdx.x; blk < p.NB_N; blk += nb)
        dev_mask_group(blk, t, p);
}

// ---- fallback kernels (R12 structure, thin wrappers) -----------------------
__global__ __launch_bounds__(256) void fb_pack_phaseA(GP p) {
    __shared__ int hist[512];
    __shared__ int gbase[512];
    __shared__ ushortT rnk[4096];
    const int t = (int)threadIdx.x;
    if ((int)blockIdx.x < 18) {
        dev_pack_init((int)blockIdx.x * 256 + t, p);
        return;
    }
    dev_phaseA_chunk((int)blockIdx.x - 18, t, hist, gbase, rnk, p);
}
__global__ __launch_bounds__(256) void fb_gemm1_phaseB(GP p) {
    __shared__ int lcnt[128];
    const int t = (int)threadIdx.x;
    if ((int)blockIdx.x < p.NBINS) {
        dev_phaseB_bin((int)blockIdx.x, t, lcnt, p);
        return;
    }
    dev_gemm1_tile((int)blockIdx.x - p.NBINS, t, p);
}
__global__ void fb_agg1(GP p)   { dev_agg1_group((int)blockIdx.x, (int)threadIdx.x, p); }
__global__ void fb_agg2(GP p)   { dev_agg2_group((int)blockIdx.x, (int)threadIdx.x, p); }
__global__ __launch_bounds__(256) void fb_gemm23(GP p) {
    dev_gemm23_tile((int)blockIdx.x, (int)threadIdx.x, p);
}
__global__ void fb_agg3min(GP p) {
    __shared__ float smin[4];
    dev_agg3min_group((int)blockIdx.x, (int)threadIdx.x, smin, p);
}
__global__ void fb_mask(GP p)   { dev_mask_group((int)blockIdx.x, (int)threadIdx.x, p); }

// ---------------------------------------------------------------------------
extern "C" void kernel_launch(void* const* d_in, const int* in_sizes, int n_in,
                              void* d_out, int out_size, void* d_ws, size_t ws_size,
                              hipStream_t stream) {
    const int N = in_sizes[0] / 128;  // 50000
    const int E = in_sizes[1];        // 800000

    char* pw = (char*)d_ws;
    auto alloc = [&](size_t bytes) -> void* {
        void* r = (void*)pw;
        pw += ((bytes + 255) / 256) * 256;
        return r;
    };
    GP p;
    p.x      = (const float*)d_in[0];
    p.src    = (const int*)d_in[1];
    p.dst    = (const int*)d_in[2];
    p.et     = (const int*)d_in[3];
    p.cellsz = (const int*)d_in[4];
    p.maxsz  = (const int*)d_in[5];
    p.W1     = (const float*)d_in[6];
    p.loop1  = (const float*)d_in[7];
    p.b1     = (const float*)d_in[8];
    p.W2     = (const float*)d_in[9];
    p.loop2  = (const float*)d_in[10];
    p.b2     = (const float*)d_in[11];
    p.W3     = (const float*)d_in[12];
    p.loop3  = (const float*)d_in[13];
    p.b3     = (const float*)d_in[14];
    p.out    = (float*)d_out;

    p.hrelb  = (ushortT*)alloc((size_t)2 * N * 64 * 2);  // 12.8 MB bf16
    p.H1b    = (ushortT*)alloc((size_t)N * 64 * 2);      //  6.4 MB bf16
    p.Sb     = (ushortT*)alloc((size_t)2 * N * 64 * 2);  // 12.8 MB bf16
    p.hrel3  = (float*)alloc((size_t)2 * N * 2 * 4);
    p.H3     = (float*)alloc((size_t)N * 2 * 4);
    p.cnt    = (int*)alloc((size_t)N * 4);
    p.eidx   = (int*)alloc((size_t)N * STRIDE * 4);      // 12.8 MB
    p.BP1    = (ushortT*)alloc((size_t)3072 * 8 * 2);    // 48 KB
    p.BP2    = (ushortT*)alloc((size_t)1536 * 8 * 2);    // 24 KB
    p.minval = (float*)alloc(4);

    const int NBINS = (N + 127) >> 7;                    // 391
    p.bincnt = (int*)alloc((size_t)NBINS * 4);
    p.binbuf = (int2*)alloc((size_t)NBINS * BINCAP * 8); // 8.0 MB

    p.N = N; p.E = E; p.NBINS = NBINS;
    p.NBA    = (E + 4095) / 4096;    // 196
    p.NTILES = (N + 63) / 64;        // 782
    p.NB_W   = (N + 3) / 4;          // 12500
    p.NB_N   = (N + 255) / 256;      // 196
    (void)ws_size; (void)n_in; (void)out_size;

    // bincnt zeroed before any phase-A atomics (both paths)
    hipMemsetAsync(p.bincnt, 0, (size_t)NBINS * 4, stream);

    // ---- try single cooperative dispatch -----------------------------------
    int dev = 0;
    hipGetDevice(&dev);
    hipDeviceProp_t prop;
    bool coop = (hipGetDeviceProperties(&prop, dev) == hipSuccess) &&
                (prop.cooperativeLaunch != 0);
    int grid = 0;
    if (coop) {
        int maxBlk = 0;
        if (hipOccupancyMaxActiveBlocksPerMultiprocessor(
                &maxBlk, (const void*)mega_kernel, 256, 0) == hipSuccess &&
            maxBlk > 0) {
            grid = maxBlk * prop.multiProcessorCount;
            if (grid > 2048) grid = 2048;
        }
    }
    if (grid >= 256) {
        void* args[] = { (void*)&p };
        hipError_t e = hipLaunchCooperativeKernel(
            (const void*)mega_kernel, dim3(grid), dim3(256), args, 0, stream);
        if (e == hipSuccess) return;
    }

    // ---- fallback: R12 8-dispatch path -------------------------------------
    fb_pack_phaseA<<<18 + p.NBA, 256, 0, stream>>>(p);
    fb_gemm1_phaseB<<<p.NBINS + p.NTILES, 256, 0, stream>>>(p);
    fb_agg1<<<p.NB_W, 256, 0, stream>>>(p);
    fb_agg2<<<p.NB_W, 256, 0, stream>>>(p);
    fb_gemm23<<<p.NTILES, 256, 0, stream>>>(p);
    fb_agg3min<<<p.NB_N, 256, 0, stream>>>(p);
    fb_mask<<<p.NB_N, 256, 0, stream>>>(p);
}